// Round 13
// baseline (165.695 us; speedup 1.0000x reference)
//
#include <hip/hip_runtime.h>

#define NTOT 8192
#define CDIM 512
#define KCL 27

typedef __attribute__((ext_vector_type(8))) short short8;
typedef __attribute__((ext_vector_type(4))) float f32x4;

static __device__ __forceinline__ unsigned short f2bf(float v) {
  union { float f; unsigned u; } z; z.f = v;
  unsigned r = (z.u + 0x7FFFu + ((z.u >> 16) & 1u)) >> 16;
  return (unsigned short)r;
}

static __device__ __forceinline__ void gld16(const unsigned short* g, char* l) {
  __builtin_amdgcn_global_load_lds(
      (const __attribute__((address_space(1))) void*)g,
      (__attribute__((address_space(3))) void*)l, 16, 0, 0);
}

// ---------------- K1 (merged): pixel inv-norms (float4) + cluster normalize ----------------
// blocks 0..127: invn for 64 pixels each; blocks 128..154: one cluster row each.
__global__ __launch_bounds__(256) void k_prep(const float* __restrict__ x,
    const float* __restrict__ clusters, float* __restrict__ invn,
    unsigned short* __restrict__ nclb) {
  __shared__ float part[16][64];
  __shared__ float sc[4];
  int bid = blockIdx.x;
  int t = threadIdx.x;
  if (bid < 128) {
    int rg = t >> 4, cgp = t & 15;
    int pix0 = bid * 64;
    int b = pix0 >> 12, hw0 = pix0 & 4095;
    const f32x4* xb4 = (const f32x4*)(x + (size_t)b * CDIM * 4096 + hw0);
    f32x4 ss4 = (f32x4){0.f, 0.f, 0.f, 0.f};
    for (int c = rg; c < CDIM; c += 16) {
      f32x4 v = xb4[(size_t)c * 1024 + cgp];
      ss4 += v * v;
    }
    *(f32x4*)&part[rg][cgp * 4] = ss4;
    __syncthreads();
    if (t < 64) {
      float s2 = 0.f;
#pragma unroll
      for (int i = 0; i < 16; ++i) s2 += part[i][t];
      invn[pix0 + t] = 1.f / fmaxf(sqrtf(s2), 1e-12f);
    }
  } else {
    int k = bid - 128;
    const float* row = clusters + (size_t)k * CDIM;
    float ss = 0.f;
    for (int c = t; c < CDIM; c += 256) { float v = row[c]; ss += v * v; }
    for (int o = 32; o; o >>= 1) ss += __shfl_down(ss, o);
    if ((t & 63) == 0) sc[t >> 6] = ss;
    __syncthreads();
    float tot = sc[0] + sc[1] + sc[2] + sc[3];
    float inv = 1.f / fmaxf(sqrtf(tot), 1e-12f);
    for (int c = t; c < CDIM; c += 256) nclb[(size_t)k * CDIM + c] = f2bf(row[c] * inv);
  }
}

// ---------------- K2b: permute(0,3,2,1)+scale -> mbf bf16 [N][C]; 512 blocks (4 c-slices) ----------------
__global__ __launch_bounds__(256) void k_merged2(const float* __restrict__ x,
    const float* __restrict__ invn, unsigned short* __restrict__ mbf) {
  __shared__ float inv[64];
  __shared__ float tile[64][65];
  int bid = blockIdx.x;
  int bh = bid >> 2, cq = bid & 3;
  int b = bh >> 6, h = bh & 63;
  int t = threadIdx.x;
  int w = t & 63, cg = t >> 6;
  const float* xb = x + (size_t)b * CDIM * 4096 + (size_t)h * 64; // xb[c*4096 + w]
  if (t < 64) inv[t] = invn[b * 4096 + h * 64 + t];
  __syncthreads();
  for (int c0 = cq * 128; c0 < cq * 128 + 128; c0 += 64) {
#pragma unroll
    for (int q = 0; q < 16; ++q) {
      int c = cg + q * 4;
      tile[c][w] = xb[(size_t)(c0 + c) * 4096 + w];
    }
    __syncthreads();
#pragma unroll
    for (int q = 0; q < 16; ++q) {
      int ww = cg + q * 4;
      int n = b * 4096 + ww * 64 + h;          // n from permute(0,3,2,1)
      mbf[(size_t)n * CDIM + c0 + w] = f2bf(tile[w][ww] * inv[ww]);
    }
    __syncthreads();
  }
}

// ---------------- K3 (MFMA): inner = mbf @ nclb^T; softmax/log_softmax/max; sT, sxbf, out_cp, maxv ----------------
__global__ __launch_bounds__(256) void k_inner2(const unsigned short* __restrict__ mbf,
    const unsigned short* __restrict__ nclb, const float* __restrict__ alpha_p,
    float* __restrict__ sT, float* __restrict__ maxv,
    float* __restrict__ out_cp, unsigned short* __restrict__ sxbf) {
  __shared__ float red[4][32][33];
  __shared__ float innerS[32][33];
  __shared__ float rowml[32], rowls[32], rowinv[32];
  int t = threadIdx.x;
  int wv = t >> 6, lane = t & 63;
  int r15 = lane & 15, kgrp = lane >> 4;
  int I0 = blockIdx.x * 32;
  float alpha = alpha_p[0];

  f32x4 acc[2][2];
#pragma unroll
  for (int m = 0; m < 2; ++m)
#pragma unroll
    for (int n = 0; n < 2; ++n) acc[m][n] = (f32x4){0.f, 0.f, 0.f, 0.f};

#pragma unroll
  for (int ks = 0; ks < 4; ++ks) {
    int kbase = wv * 128 + ks * 32 + kgrp * 8;
    short8 a[2], b[2];
#pragma unroll
    for (int m = 0; m < 2; ++m)
      a[m] = *(const short8*)(mbf + (size_t)(I0 + m * 16 + r15) * CDIM + kbase);
#pragma unroll
    for (int n = 0; n < 2; ++n)
      b[n] = *(const short8*)(nclb + (size_t)(n * 16 + r15) * CDIM + kbase);
#pragma unroll
    for (int m = 0; m < 2; ++m)
#pragma unroll
      for (int n = 0; n < 2; ++n)
        acc[m][n] = __builtin_amdgcn_mfma_f32_16x16x32_bf16(a[m], b[n], acc[m][n], 0, 0, 0);
  }
#pragma unroll
  for (int m = 0; m < 2; ++m)
#pragma unroll
    for (int n = 0; n < 2; ++n)
#pragma unroll
      for (int reg = 0; reg < 4; ++reg)
        red[wv][m * 16 + kgrp * 4 + reg][n * 16 + r15] = acc[m][n][reg];
  __syncthreads();
  for (int idx = t; idx < 1024; idx += 256) {
    int r = idx >> 5, c = idx & 31;
    innerS[r][c] = red[0][r][c] + red[1][r][c] + red[2][r][c] + red[3][r][c];
  }
  __syncthreads();
  if (t < 32) {
    float mi = -3.4e38f, ml = -3.4e38f;
    for (int k = 0; k < KCL; ++k) {
      float iv = innerS[t][k];
      mi = fmaxf(mi, iv);
      ml = fmaxf(ml, alpha * iv);
    }
    float sum = 0.f;
    for (int k = 0; k < KCL; ++k) sum += expf(alpha * innerS[t][k] - ml);
    rowml[t] = ml;
    rowls[t] = ml + logf(sum);
    rowinv[t] = 1.f / sum;
    maxv[I0 + t] = mi;
    sxbf[I0 + t] = 0x3F80;                     // Sx row 0 = 1.0
  }
  __syncthreads();
  for (int idx = t; idx < 32 * KCL; idx += 256) {
    int r = idx / KCL, k = idx - r * KCL;
    int n = I0 + r;
    float iv = innerS[r][k];
    float sv = expf(alpha * iv - rowml[r]) * rowinv[r];
    sT[(size_t)k * NTOT + n] = sv;
    sxbf[(size_t)(k + 1) * NTOT + n] = f2bf(sv);
    int b = n >> 12, w = (n >> 6) & 63, h = n & 63;
    out_cp[(((size_t)b * KCL + k) * 64 + h) * 64 + w] = alpha * iv - rowls[r];
  }
}

// ---------------- K4 (fused): Rpart[jc][28][N] = relu(Mi Mj^T, diag=0) @ [1|S] ----------------
// 3-buffer staging rotation: ONE barrier per K-step (step k computes buf[k%3],
// ISSUEs k+2 into buf[(k+2)%3] = buffer last read at step k-1, protected by the
// top-of-step barrier). Counted vmcnt(4), 2-deep. Prow aliases b0+b1. LDS 57344.
__global__ __launch_bounds__(256) void k_fused(const unsigned short* __restrict__ Mb,
    const unsigned short* __restrict__ sxT, float* __restrict__ Rpart) {
  __shared__ char lds[57344];
  char* b0   = lds;             // [0,16K):  J at +0, I at +8K
  char* b1   = lds + 16384;     // [16K,32K)
  char* b2   = lds + 32768;     // [32K,48K)
  char* Prow = lds;             // [0,32K) aliases b0,b1 (live: epilogue..PV)
  char* Sx   = lds + 49152;     // [48K,56K)
  int t = threadIdx.x;
  int wid = t >> 6, lane = t & 63;
  int r15 = lane & 15, kgrp = lane >> 4;
  int wrj = wid >> 1, wci = wid & 1;
  int I0 = blockIdx.x * 128;
  int Jbase = blockIdx.y * 512;

  f32x4 pv[2][2];
#pragma unroll
  for (int m = 0; m < 2; ++m)
#pragma unroll
    for (int n = 0; n < 2; ++n) pv[m][n] = (f32x4){0.f, 0.f, 0.f, 0.f};

  // QK staging: linear LDS dest; pre-swizzled global source col (slot ^ (row&3)).
  int srow = wid * 16 + (lane >> 2);
  int scol = (((lane & 3) ^ ((lane >> 2) & 3)) * 8);   // elements
  int ldst = wid * 1024;
  const unsigned short* gI0 = Mb + (size_t)(I0 + srow) * CDIM + scol;
  const unsigned short* gI1 = Mb + (size_t)(I0 + 64 + srow) * CDIM + scol;

  // Sx staging geometry
  int sx_c_local = wid * 4 + (lane >> 4);
  int sx_slot = lane & 15;

  for (int jt = 0; jt < 4; ++jt) {
    int J0 = Jbase + jt * 128;
    const unsigned short* gJ0 = Mb + (size_t)(J0 + srow) * CDIM + scol;
    const unsigned short* gJ1 = Mb + (size_t)(J0 + 64 + srow) * CDIM + scol;

    __syncthreads();   // prev jt's PV readers done before Sx/staging overwrite

    // Sx tile [32 c][128 j] via async gld16, source pre-swizzled
#pragma unroll
    for (int r2 = 0; r2 < 2; ++r2) {
      int c = r2 * 16 + sx_c_local;
      int j = ((sx_slot ^ (c & 15)) * 8);
      gld16(sxT + (size_t)c * NTOT + J0 + j, Sx + (r2 * 16 + wid * 4) * 256);
    }

#define ISSUE(KS, B)                                                           \
    { gld16(gJ0 + (KS) * 32, (B) + ldst);                                      \
      gld16(gJ1 + (KS) * 32, (B) + 4096 + ldst);                               \
      gld16(gI0 + (KS) * 32, (B) + 8192 + ldst);                               \
      gld16(gI1 + (KS) * 32, (B) + 12288 + ldst); }

#define QKSTEP(B)                                                              \
    {                                                                          \
      short8 a[4], b[4];                                                       \
      _Pragma("unroll")                                                        \
      for (int m = 0; m < 4; ++m)                                              \
        a[m] = *(const short8*)((B) + ((wrj * 64 + m * 16 + r15) * 64 +        \
                                       ((kgrp * 16) ^ ((r15 & 3) << 4))));     \
      _Pragma("unroll")                                                        \
      for (int n = 0; n < 4; ++n)                                              \
        b[n] = *(const short8*)((B) + 8192 + ((wci * 64 + n * 16 + r15) * 64 + \
                                       ((kgrp * 16) ^ ((r15 & 3) << 4))));     \
      _Pragma("unroll")                                                        \
      for (int m = 0; m < 4; ++m)                                              \
        _Pragma("unroll")                                                      \
        for (int n = 0; n < 4; ++n)                                            \
          acc[m][n] = __builtin_amdgcn_mfma_f32_16x16x32_bf16(a[m], b[n], acc[m][n], 0, 0, 0); \
    }

#define STEP(ISS_KS, ISS_B, COMP_B)                                            \
    asm volatile("s_waitcnt vmcnt(4)" ::: "memory");                           \
    __builtin_amdgcn_s_barrier();                                              \
    ISSUE(ISS_KS, ISS_B);                                                      \
    __builtin_amdgcn_sched_barrier(0);                                         \
    QKSTEP(COMP_B);                                                            \
    __builtin_amdgcn_sched_barrier(0);

    // prologue: 2-deep prefetch
    ISSUE(0, b0);
    ISSUE(1, b1);

    f32x4 acc[4][4];
#pragma unroll
    for (int m = 0; m < 4; ++m)
#pragma unroll
      for (int n = 0; n < 4; ++n) acc[m][n] = (f32x4){0.f, 0.f, 0.f, 0.f};

    // steps 0..11: 4 iterations x 3 steps (buf rotation b0,b1,b2)
#pragma unroll 1
    for (int kk = 0; kk < 12; kk += 3) {
      STEP(kk + 2, b2, b0)
      STEP(kk + 3, b0, b1)
      STEP(kk + 4, b1, b2)
    }
    // epilogue steps 12..15
    STEP(14, b2, b0)
    STEP(15, b0, b1)
    // step 14 (no issue)
    asm volatile("s_waitcnt vmcnt(4)" ::: "memory");
    __builtin_amdgcn_s_barrier();
    __builtin_amdgcn_sched_barrier(0);
    QKSTEP(b2)
    __builtin_amdgcn_sched_barrier(0);
    // step 15 (no issue, drain)
    asm volatile("s_waitcnt vmcnt(0)" ::: "memory");
    __builtin_amdgcn_s_barrier();
    __builtin_amdgcn_sched_barrier(0);
    QKSTEP(b0)
    __builtin_amdgcn_sched_barrier(0);
    __builtin_amdgcn_s_barrier();   // all QK reads done -> Prow may overwrite b0/b1
#undef STEP
#undef QKSTEP
#undef ISSUE

    // acc = P^T tile: row j = wrj*64+m*16+kgrp*4+reg, col i = wci*64+n*16+r15.
#pragma unroll
    for (int m = 0; m < 4; ++m) {
#pragma unroll
      for (int n = 0; n < 4; ++n) {
        int iloc = wci * 64 + n * 16 + r15;
        int gi = I0 + iloc;
        int jloc = wrj * 64 + m * 16 + kgrp * 4;
        int gj = J0 + jloc;
        unsigned short h[4];
#pragma unroll
        for (int reg = 0; reg < 4; ++reg) {
          float v = acc[m][n][reg];
          v = v > 0.f ? v : 0.f;
          if (gj + reg == gi) v = 0.f;
          h[reg] = f2bf(v);
        }
        uint2 pk;
        pk.x = (unsigned)h[0] | ((unsigned)h[1] << 16);
        pk.y = (unsigned)h[2] | ((unsigned)h[3] << 16);
        *(uint2*)(Prow + iloc * 256 + ((jloc * 2) ^ ((iloc & 15) << 4))) = pk;
      }
    }
    __syncthreads();

    // PV: pv += Ptile(128x128) @ Sx(128x32); wave owns rows wid*32..+32
#pragma unroll
    for (int ks = 0; ks < 4; ++ks) {
      short8 a2[2], b2v[2];
#pragma unroll
      for (int m2 = 0; m2 < 2; ++m2) {
        int iloc = wid * 32 + m2 * 16 + r15;
        a2[m2] = *(const short8*)(Prow + iloc * 256 +
                                  ((ks * 64 + kgrp * 16) ^ ((iloc & 15) << 4)));
      }
#pragma unroll
      for (int n2 = 0; n2 < 2; ++n2) {
        int c = n2 * 16 + r15;
        b2v[n2] = *(const short8*)(Sx + c * 256 +
                                   ((ks * 64 + kgrp * 16) ^ ((c & 15) << 4)));
      }
#pragma unroll
      for (int m2 = 0; m2 < 2; ++m2)
#pragma unroll
        for (int n2 = 0; n2 < 2; ++n2)
          pv[m2][n2] = __builtin_amdgcn_mfma_f32_16x16x32_bf16(a2[m2], b2v[n2], pv[m2][n2], 0, 0, 0);
    }
  }

  // write transposed Rpart[jc][c][gi]: 4 consecutive gi per lane -> float4 store
#pragma unroll
  for (int m2 = 0; m2 < 2; ++m2) {
#pragma unroll
    for (int n2 = 0; n2 < 2; ++n2) {
      int c = n2 * 16 + r15;
      if (c < 28) {
        int gi = I0 + wid * 32 + m2 * 16 + kgrp * 4;
        *(f32x4*)(&Rpart[((size_t)blockIdx.y * 28 + c) * NTOT + gi]) = pv[m2][n2];
      }
    }
  }
}

// ---------------- K6 (MFMA syrk): Gpart[kb][32][32] = Sx(:, kb-chunk) Sx^T ----------------
__global__ __launch_bounds__(256) void k_sts2(const unsigned short* __restrict__ sxbf,
    float* __restrict__ Gpart) {
  __shared__ float red[4][32][33];
  int t = threadIdx.x;
  int wv = t >> 6, lane = t & 63;
  int r15 = lane & 15, kgrp = lane >> 4;
  int kbase = blockIdx.x * 128 + wv * 32 + kgrp * 8;
  short8 a[2];
#pragma unroll
  for (int m = 0; m < 2; ++m)
    a[m] = *(const short8*)(sxbf + (size_t)(m * 16 + r15) * NTOT + kbase);
  f32x4 g4[2][2];
#pragma unroll
  for (int m = 0; m < 2; ++m)
#pragma unroll
    for (int n = 0; n < 2; ++n) {
      g4[m][n] = (f32x4){0.f, 0.f, 0.f, 0.f};
      g4[m][n] = __builtin_amdgcn_mfma_f32_16x16x32_bf16(a[m], a[n], g4[m][n], 0, 0, 0);
    }
#pragma unroll
  for (int m = 0; m < 2; ++m)
#pragma unroll
    for (int n = 0; n < 2; ++n)
#pragma unroll
      for (int reg = 0; reg < 4; ++reg)
        red[wv][m * 16 + kgrp * 4 + reg][n * 16 + r15] = g4[m][n][reg];
  __syncthreads();
  for (int idx = t; idx < 1024; idx += 256) {
    int r = idx >> 5, c = idx & 31;
    Gpart[(size_t)blockIdx.x * 1024 + idx] = red[0][r][c] + red[1][r][c] + red[2][r][c] + red[3][r][c];
  }
}

// ---------------- K7a: grid-parallel reduction of Rpart -> 128x30 partials ----------------
__global__ __launch_bounds__(64) void k_reduce1(const float* __restrict__ Rpart,
    const float* __restrict__ sT, const float* __restrict__ maxv,
    float* __restrict__ partials) {
  int t = threadIdx.x;
  int n = blockIdx.x * 64 + t;
  float rsum[28];
#pragma unroll
  for (int c = 0; c < 28; ++c) rsum[c] = 0.f;
#pragma unroll
  for (int bs = 0; bs < 16; ++bs)
#pragma unroll
    for (int c = 0; c < 28; ++c)
      rsum[c] += Rpart[((size_t)bs * 28 + c) * NTOT + n];
  float deg = rsum[0];
  float T1 = 0.f;
  float vloc[KCL];
#pragma unroll
  for (int k = 0; k < KCL; ++k) {
    float sv = sT[(size_t)k * NTOT + n];
    T1 += sv * rsum[1 + k];
    vloc[k] = deg * sv;
  }
  float mx = maxv[n];
  for (int o = 32; o; o >>= 1) {
    deg += __shfl_down(deg, o);
    T1 += __shfl_down(T1, o);
    mx += __shfl_down(mx, o);
  }
#pragma unroll
  for (int k = 0; k < KCL; ++k)
    for (int o = 32; o; o >>= 1) vloc[k] += __shfl_down(vloc[k], o);
  if (t == 0) {
    float* p = partials + blockIdx.x * 30;
    p[0] = deg; p[1] = T1; p[2] = mx;
#pragma unroll
    for (int k = 0; k < KCL; ++k) p[3 + k] = vloc[k];
  }
}

// ---------------- K7b: tiny final combine + ortho ----------------
__device__ float block_sum_1024(float v) {
  __shared__ float sc[16];
  for (int o = 32; o; o >>= 1) v += __shfl_down(v, o);
  __syncthreads();
  if ((threadIdx.x & 63) == 0) sc[threadIdx.x >> 6] = v;
  __syncthreads();
  if (threadIdx.x == 0) {
    float r = 0.f;
    for (int i = 0; i < 16; ++i) r += sc[i];
    sc[0] = r;
  }
  __syncthreads();
  return sc[0];
}

__global__ __launch_bounds__(1024) void k_final2(const float* __restrict__ partials,
    const float* __restrict__ Gpart, float* __restrict__ out) {
  __shared__ float comb[30];
  int t = threadIdx.x;
  if (t < 30) {
    float a = 0.f;
    for (int b = 0; b < 128; ++b) a += partials[b * 30 + t];
    comb[t] = a;
  }
  float val = 0.f;
  if (t < 729) {
    int k = t / 27, l = t - k * 27;
    int gidx = (k + 1) * 32 + (l + 1);
    for (int b = 0; b < 64; ++b) val += Gpart[(size_t)b * 1024 + gidx];
  }
  __syncthreads();
  float F2 = block_sum_1024(val * val);
  float F = sqrtf(F2);
  bool diag = (t < 729) && (t % 28 == 0);
  float gg = (t < 729) ? (val / F - (diag ? (1.f / sqrtf(27.f)) : 0.f)) : 0.f;
  float O2 = block_sum_1024(gg * gg);
  float ortho = sqrtf(O2);
  if (t == 0) {
    float sumDeg = comb[0], T1 = comb[1], maxsum = comb[2];
    float norm = 0.5f * sumDeg;
    float vv = 0.f;
    for (int k = 0; k < KCL; ++k) vv += comb[3 + k] * comb[3 + k];
    float c = 0.05f / (2.f * norm);
    float sm = -(T1 - c * vv) / (2.f * norm);
    float cl = -maxsum / (float)NTOT;
    out[0] = sm + cl + ortho;
    out[1] = sm;
  }
}

extern "C" void kernel_launch(void* const* d_in, const int* in_sizes, int n_in,
                              void* d_out, int out_size, void* d_ws, size_t ws_size,
                              hipStream_t stream) {
  const float* x        = (const float*)d_in[0];
  const float* clusters = (const float*)d_in[1];
  const float* alpha    = (const float*)d_in[2];
  float* out = (float*)d_out;
  float* ws  = (float*)d_ws;

  // workspace layout (float offsets)
  const size_t OFF_MBF  = 0;                                    // bf16 [8192][512]
  const size_t OFF_NCLB = (size_t)NTOT * CDIM / 2;              // bf16 [32][512]
  const size_t OFF_ST   = OFF_NCLB + (size_t)32 * CDIM / 2;     // f32 sT [27][8192]
  const size_t OFF_SXB  = OFF_ST + (size_t)NTOT * KCL;          // bf16 sxT [32][8192]
  const size_t OFF_MAXV = OFF_SXB + (size_t)32 * NTOT / 2;
  const size_t OFF_INVN = OFF_MAXV + NTOT;                      // f32 [8192]
  const size_t OFF_R    = OFF_INVN + NTOT;                      // Rpart: 16*28*8192 f32
  const size_t OFF_GP   = OFF_R + (size_t)16 * 28 * NTOT;       // Gpart: 64*1024 f32
  const size_t OFF_PART = OFF_GP + (size_t)64 * 1024;           // 128*30 partials

  unsigned short* mbf  = (unsigned short*)(ws + OFF_MBF);
  unsigned short* nclb = (unsigned short*)(ws + OFF_NCLB);
  unsigned short* sxbf = (unsigned short*)(ws + OFF_SXB);

  // no memsets needed: nclb rows 27-31 / sxbf rows 28-31 feed only output
  // columns >= 28, which are never read (PV write guarded c<28; k_final2
  // reads Gpart indices 1..27 only). Contents are replay-invariant.
  k_prep<<<155, 256, 0, stream>>>(x, clusters, ws + OFF_INVN, nclb);
  k_merged2<<<512, 256, 0, stream>>>(x, ws + OFF_INVN, mbf);
  k_inner2<<<256, 256, 0, stream>>>(mbf, nclb, alpha,
                                    ws + OFF_ST, ws + OFF_MAXV, out + 2, sxbf);
  k_fused<<<dim3(64, 16), 256, 0, stream>>>(mbf, sxbf, ws + OFF_R);
  k_sts2<<<64, 256, 0, stream>>>(sxbf, ws + OFF_GP);
  k_reduce1<<<128, 64, 0, stream>>>(ws + OFF_R, ws + OFF_ST, ws + OFF_MAXV,
                                    ws + OFF_PART);
  k_final2<<<1, 1024, 0, stream>>>(ws + OFF_PART, ws + OFF_GP, out);
}

// Round 14
// 151.711 us; speedup vs baseline: 1.0922x; 1.0922x over previous
//
#include <hip/hip_runtime.h>

#define NTOT 8192
#define CDIM 512
#define KCL 27

typedef __attribute__((ext_vector_type(8))) short short8;
typedef __attribute__((ext_vector_type(4))) float f32x4;

static __device__ __forceinline__ unsigned short f2bf(float v) {
  union { float f; unsigned u; } z; z.f = v;
  unsigned r = (z.u + 0x7FFFu + ((z.u >> 16) & 1u)) >> 16;
  return (unsigned short)r;
}

static __device__ __forceinline__ void gld16(const unsigned short* g, char* l) {
  __builtin_amdgcn_global_load_lds(
      (const __attribute__((address_space(1))) void*)g,
      (__attribute__((address_space(3))) void*)l, 16, 0, 0);
}

// ---------------- K1 (merged): pixel inv-norms (float4) + cluster normalize ----------------
__global__ __launch_bounds__(256) void k_prep(const float* __restrict__ x,
    const float* __restrict__ clusters, float* __restrict__ invn,
    unsigned short* __restrict__ nclb) {
  __shared__ float part[16][64];
  __shared__ float sc[4];
  int bid = blockIdx.x;
  int t = threadIdx.x;
  if (bid < 128) {
    int rg = t >> 4, cgp = t & 15;
    int pix0 = bid * 64;
    int b = pix0 >> 12, hw0 = pix0 & 4095;
    const f32x4* xb4 = (const f32x4*)(x + (size_t)b * CDIM * 4096 + hw0);
    f32x4 ss4 = (f32x4){0.f, 0.f, 0.f, 0.f};
    for (int c = rg; c < CDIM; c += 16) {
      f32x4 v = xb4[(size_t)c * 1024 + cgp];
      ss4 += v * v;
    }
    *(f32x4*)&part[rg][cgp * 4] = ss4;
    __syncthreads();
    if (t < 64) {
      float s2 = 0.f;
#pragma unroll
      for (int i = 0; i < 16; ++i) s2 += part[i][t];
      invn[pix0 + t] = 1.f / fmaxf(sqrtf(s2), 1e-12f);
    }
  } else {
    int k = bid - 128;
    const float* row = clusters + (size_t)k * CDIM;
    float ss = 0.f;
    for (int c = t; c < CDIM; c += 256) { float v = row[c]; ss += v * v; }
    for (int o = 32; o; o >>= 1) ss += __shfl_down(ss, o);
    if ((t & 63) == 0) sc[t >> 6] = ss;
    __syncthreads();
    float tot = sc[0] + sc[1] + sc[2] + sc[3];
    float inv = 1.f / fmaxf(sqrtf(tot), 1e-12f);
    for (int c = t; c < CDIM; c += 256) nclb[(size_t)k * CDIM + c] = f2bf(row[c] * inv);
  }
}

// ---------------- K2b: permute(0,3,2,1)+scale -> mbf bf16 [N][C]; 512 blocks (4 c-slices) ----------------
__global__ __launch_bounds__(256) void k_merged2(const float* __restrict__ x,
    const float* __restrict__ invn, unsigned short* __restrict__ mbf) {
  __shared__ float inv[64];
  __shared__ float tile[64][65];
  int bid = blockIdx.x;
  int bh = bid >> 2, cq = bid & 3;
  int b = bh >> 6, h = bh & 63;
  int t = threadIdx.x;
  int w = t & 63, cg = t >> 6;
  const float* xb = x + (size_t)b * CDIM * 4096 + (size_t)h * 64; // xb[c*4096 + w]
  if (t < 64) inv[t] = invn[b * 4096 + h * 64 + t];
  __syncthreads();
  for (int c0 = cq * 128; c0 < cq * 128 + 128; c0 += 64) {
#pragma unroll
    for (int q = 0; q < 16; ++q) {
      int c = cg + q * 4;
      tile[c][w] = xb[(size_t)(c0 + c) * 4096 + w];
    }
    __syncthreads();
#pragma unroll
    for (int q = 0; q < 16; ++q) {
      int ww = cg + q * 4;
      int n = b * 4096 + ww * 64 + h;          // n from permute(0,3,2,1)
      mbf[(size_t)n * CDIM + c0 + w] = f2bf(tile[w][ww] * inv[ww]);
    }
    __syncthreads();
  }
}

// ---------------- K3 (MFMA): inner = mbf @ nclb^T; softmax/log_softmax/max; sT, sxbf, out_cp, maxv ----------------
__global__ __launch_bounds__(256) void k_inner2(const unsigned short* __restrict__ mbf,
    const unsigned short* __restrict__ nclb, const float* __restrict__ alpha_p,
    float* __restrict__ sT, float* __restrict__ maxv,
    float* __restrict__ out_cp, unsigned short* __restrict__ sxbf) {
  __shared__ float red[4][32][33];
  __shared__ float innerS[32][33];
  __shared__ float rowml[32], rowls[32], rowinv[32];
  int t = threadIdx.x;
  int wv = t >> 6, lane = t & 63;
  int r15 = lane & 15, kgrp = lane >> 4;
  int I0 = blockIdx.x * 32;
  float alpha = alpha_p[0];

  f32x4 acc[2][2];
#pragma unroll
  for (int m = 0; m < 2; ++m)
#pragma unroll
    for (int n = 0; n < 2; ++n) acc[m][n] = (f32x4){0.f, 0.f, 0.f, 0.f};

#pragma unroll
  for (int ks = 0; ks < 4; ++ks) {
    int kbase = wv * 128 + ks * 32 + kgrp * 8;
    short8 a[2], b[2];
#pragma unroll
    for (int m = 0; m < 2; ++m)
      a[m] = *(const short8*)(mbf + (size_t)(I0 + m * 16 + r15) * CDIM + kbase);
#pragma unroll
    for (int n = 0; n < 2; ++n)
      b[n] = *(const short8*)(nclb + (size_t)(n * 16 + r15) * CDIM + kbase);
#pragma unroll
    for (int m = 0; m < 2; ++m)
#pragma unroll
      for (int n = 0; n < 2; ++n)
        acc[m][n] = __builtin_amdgcn_mfma_f32_16x16x32_bf16(a[m], b[n], acc[m][n], 0, 0, 0);
  }
#pragma unroll
  for (int m = 0; m < 2; ++m)
#pragma unroll
    for (int n = 0; n < 2; ++n)
#pragma unroll
      for (int reg = 0; reg < 4; ++reg)
        red[wv][m * 16 + kgrp * 4 + reg][n * 16 + r15] = acc[m][n][reg];
  __syncthreads();
  for (int idx = t; idx < 1024; idx += 256) {
    int r = idx >> 5, c = idx & 31;
    innerS[r][c] = red[0][r][c] + red[1][r][c] + red[2][r][c] + red[3][r][c];
  }
  __syncthreads();
  if (t < 32) {
    float mi = -3.4e38f, ml = -3.4e38f;
    for (int k = 0; k < KCL; ++k) {
      float iv = innerS[t][k];
      mi = fmaxf(mi, iv);
      ml = fmaxf(ml, alpha * iv);
    }
    float sum = 0.f;
    for (int k = 0; k < KCL; ++k) sum += expf(alpha * innerS[t][k] - ml);
    rowml[t] = ml;
    rowls[t] = ml + logf(sum);
    rowinv[t] = 1.f / sum;
    maxv[I0 + t] = mi;
    sxbf[I0 + t] = 0x3F80;                     // Sx row 0 = 1.0
  }
  __syncthreads();
  for (int idx = t; idx < 32 * KCL; idx += 256) {
    int r = idx / KCL, k = idx - r * KCL;
    int n = I0 + r;
    float iv = innerS[r][k];
    float sv = expf(alpha * iv - rowml[r]) * rowinv[r];
    sT[(size_t)k * NTOT + n] = sv;
    sxbf[(size_t)(k + 1) * NTOT + n] = f2bf(sv);
    int b = n >> 12, w = (n >> 6) & 63, h = n & 63;
    out_cp[(((size_t)b * KCL + k) * 64 + h) * 64 + w] = alpha * iv - rowls[r];
  }
}

// ---------------- K4 (fused): Rpart[jc][28][N] = relu(Mi Mj^T, diag=0) @ [1|S] ----------------
// Round-12 version (best validated): T4 counted-vmcnt (raw s_barrier + vmcnt(4),
// 2-deep, 2-buffer), async pre-swizzled Sx staging, Prow aliases staging. LDS 40960.
__global__ __launch_bounds__(256) void k_fused(const unsigned short* __restrict__ Mb,
    const unsigned short* __restrict__ sxT, float* __restrict__ Rpart) {
  __shared__ char lds[40960];
  char* bufJ0 = lds;            // [0,8K)
  char* bufI0 = lds + 8192;     // [8K,16K)
  char* bufJ1 = lds + 16384;    // [16K,24K)
  char* bufI1 = lds + 24576;    // [24K,32K)
  char* Prow  = lds;            // [0,32K) aliases all staging buffers
  char* Sx    = lds + 32768;    // [32K,40K)
  int t = threadIdx.x;
  int wid = t >> 6, lane = t & 63;
  int r15 = lane & 15, kgrp = lane >> 4;
  int wrj = wid >> 1, wci = wid & 1;
  int I0 = blockIdx.x * 128;
  int Jbase = blockIdx.y * 512;

  f32x4 pv[2][2];
#pragma unroll
  for (int m = 0; m < 2; ++m)
#pragma unroll
    for (int n = 0; n < 2; ++n) pv[m][n] = (f32x4){0.f, 0.f, 0.f, 0.f};

  // QK staging: linear LDS dest; pre-swizzled global source col (slot ^ (row&3)).
  int srow = wid * 16 + (lane >> 2);
  int scol = (((lane & 3) ^ ((lane >> 2) & 3)) * 8);   // elements
  int ldst = wid * 1024;
  const unsigned short* gI0 = Mb + (size_t)(I0 + srow) * CDIM + scol;
  const unsigned short* gI1 = Mb + (size_t)(I0 + 64 + srow) * CDIM + scol;

  // Sx staging geometry: wave wid covers c rows (r2*16 + wid*4 + lane/16), slot = lane&15
  int sx_c_local = wid * 4 + (lane >> 4);
  int sx_slot = lane & 15;

  for (int jt = 0; jt < 4; ++jt) {
    int J0 = Jbase + jt * 128;
    const unsigned short* gJ0 = Mb + (size_t)(J0 + srow) * CDIM + scol;
    const unsigned short* gJ1 = Mb + (size_t)(J0 + 64 + srow) * CDIM + scol;

    __syncthreads();   // prev jt's PV readers done before Sx/staging overwrite

    // Sx tile [32 c][128 j] via async gld16, source pre-swizzled:
    // LDS[c][slot] = sxT[c][(slot ^ (c&15))*8 ..]
#pragma unroll
    for (int r2 = 0; r2 < 2; ++r2) {
      int c = r2 * 16 + sx_c_local;
      int j = ((sx_slot ^ (c & 15)) * 8);
      gld16(sxT + (size_t)c * NTOT + J0 + j, Sx + (r2 * 16 + wid * 4) * 256);
    }

#define ISSUE(KS, BJ, BI)                                                      \
    { gld16(gJ0 + (KS) * 32, (BJ) + ldst);                                     \
      gld16(gJ1 + (KS) * 32, (BJ) + 4096 + ldst);                              \
      gld16(gI0 + (KS) * 32, (BI) + ldst);                                     \
      gld16(gI1 + (KS) * 32, (BI) + 4096 + ldst); }

#define QKSTEP(BJ, BI)                                                         \
    {                                                                          \
      short8 a[4], b[4];                                                       \
      _Pragma("unroll")                                                        \
      for (int m = 0; m < 4; ++m)                                              \
        a[m] = *(const short8*)((BJ) + ((wrj * 64 + m * 16 + r15) * 64 +       \
                                        ((kgrp * 16) ^ ((r15 & 3) << 4))));    \
      _Pragma("unroll")                                                        \
      for (int n = 0; n < 4; ++n)                                              \
        b[n] = *(const short8*)((BI) + ((wci * 64 + n * 16 + r15) * 64 +       \
                                        ((kgrp * 16) ^ ((r15 & 3) << 4))));    \
      _Pragma("unroll")                                                        \
      for (int m = 0; m < 4; ++m)                                              \
        _Pragma("unroll")                                                      \
        for (int n = 0; n < 4; ++n)                                            \
          acc[m][n] = __builtin_amdgcn_mfma_f32_16x16x32_bf16(a[m], b[n], acc[m][n], 0, 0, 0); \
    }

    // prologue: Sx (2) + 2-deep QK prefetch (8) outstanding
    ISSUE(0, bufJ0, bufI0);
    ISSUE(1, bufJ1, bufI1);

    f32x4 acc[4][4];
#pragma unroll
    for (int m = 0; m < 4; ++m)
#pragma unroll
      for (int n = 0; n < 4; ++n) acc[m][n] = (f32x4){0.f, 0.f, 0.f, 0.f};

    // steady state: wait only for loads issued 2 K-steps ago
#pragma unroll 1
    for (int kk = 0; kk < 14; kk += 2) {
      asm volatile("s_waitcnt vmcnt(4)" ::: "memory");
      __builtin_amdgcn_s_barrier();
      __builtin_amdgcn_sched_barrier(0);
      QKSTEP(bufJ0, bufI0);
      __builtin_amdgcn_sched_barrier(0);
      __builtin_amdgcn_s_barrier();
      ISSUE(kk + 2, bufJ0, bufI0);
      asm volatile("s_waitcnt vmcnt(4)" ::: "memory");
      __builtin_amdgcn_s_barrier();
      __builtin_amdgcn_sched_barrier(0);
      QKSTEP(bufJ1, bufI1);
      __builtin_amdgcn_sched_barrier(0);
      __builtin_amdgcn_s_barrier();
      ISSUE(kk + 3, bufJ1, bufI1);
    }
    // epilogue K-steps 14,15
    asm volatile("s_waitcnt vmcnt(4)" ::: "memory");
    __builtin_amdgcn_s_barrier();
    __builtin_amdgcn_sched_barrier(0);
    QKSTEP(bufJ0, bufI0);
    __builtin_amdgcn_sched_barrier(0);
    __builtin_amdgcn_s_barrier();
    asm volatile("s_waitcnt vmcnt(0)" ::: "memory");
    __builtin_amdgcn_s_barrier();
    __builtin_amdgcn_sched_barrier(0);
    QKSTEP(bufJ1, bufI1);
    __builtin_amdgcn_sched_barrier(0);
    __builtin_amdgcn_s_barrier();   // all QK reads done -> Prow may overwrite bufs
#undef QKSTEP
#undef ISSUE

    // acc = P^T tile: row j = wrj*64+m*16+kgrp*4+reg, col i = wci*64+n*16+r15.
#pragma unroll
    for (int m = 0; m < 4; ++m) {
#pragma unroll
      for (int n = 0; n < 4; ++n) {
        int iloc = wci * 64 + n * 16 + r15;
        int gi = I0 + iloc;
        int jloc = wrj * 64 + m * 16 + kgrp * 4;
        int gj = J0 + jloc;
        unsigned short h[4];
#pragma unroll
        for (int reg = 0; reg < 4; ++reg) {
          float v = acc[m][n][reg];
          v = v > 0.f ? v : 0.f;
          if (gj + reg == gi) v = 0.f;
          h[reg] = f2bf(v);
        }
        uint2 pk;
        pk.x = (unsigned)h[0] | ((unsigned)h[1] << 16);
        pk.y = (unsigned)h[2] | ((unsigned)h[3] << 16);
        *(uint2*)(Prow + iloc * 256 + ((jloc * 2) ^ ((iloc & 15) << 4))) = pk;
      }
    }
    __syncthreads();

    // PV: pv += Ptile(128x128) @ Sx(128x32); wave owns rows wid*32..+32
#pragma unroll
    for (int ks = 0; ks < 4; ++ks) {
      short8 a2[2], b2[2];
#pragma unroll
      for (int m2 = 0; m2 < 2; ++m2) {
        int iloc = wid * 32 + m2 * 16 + r15;
        a2[m2] = *(const short8*)(Prow + iloc * 256 +
                                  ((ks * 64 + kgrp * 16) ^ ((iloc & 15) << 4)));
      }
#pragma unroll
      for (int n2 = 0; n2 < 2; ++n2) {
        int c = n2 * 16 + r15;
        b2[n2] = *(const short8*)(Sx + c * 256 +
                                  ((ks * 64 + kgrp * 16) ^ ((c & 15) << 4)));
      }
#pragma unroll
      for (int m2 = 0; m2 < 2; ++m2)
#pragma unroll
        for (int n2 = 0; n2 < 2; ++n2)
          pv[m2][n2] = __builtin_amdgcn_mfma_f32_16x16x32_bf16(a2[m2], b2[n2], pv[m2][n2], 0, 0, 0);
    }
  }

  // write transposed Rpart[jc][c][gi]: 4 consecutive gi per lane -> float4 store
#pragma unroll
  for (int m2 = 0; m2 < 2; ++m2) {
#pragma unroll
    for (int n2 = 0; n2 < 2; ++n2) {
      int c = n2 * 16 + r15;
      if (c < 28) {
        int gi = I0 + wid * 32 + m2 * 16 + kgrp * 4;
        *(f32x4*)(&Rpart[((size_t)blockIdx.y * 28 + c) * NTOT + gi]) = pv[m2][n2];
      }
    }
  }
}

// ---------------- K6 (MFMA syrk): Gpart[kb][32][32] = Sx(:, kb-chunk) Sx^T ----------------
__global__ __launch_bounds__(256) void k_sts2(const unsigned short* __restrict__ sxbf,
    float* __restrict__ Gpart) {
  __shared__ float red[4][32][33];
  int t = threadIdx.x;
  int wv = t >> 6, lane = t & 63;
  int r15 = lane & 15, kgrp = lane >> 4;
  int kbase = blockIdx.x * 128 + wv * 32 + kgrp * 8;
  short8 a[2];
#pragma unroll
  for (int m = 0; m < 2; ++m)
    a[m] = *(const short8*)(sxbf + (size_t)(m * 16 + r15) * NTOT + kbase);
  f32x4 g4[2][2];
#pragma unroll
  for (int m = 0; m < 2; ++m)
#pragma unroll
    for (int n = 0; n < 2; ++n) {
      g4[m][n] = (f32x4){0.f, 0.f, 0.f, 0.f};
      g4[m][n] = __builtin_amdgcn_mfma_f32_16x16x32_bf16(a[m], a[n], g4[m][n], 0, 0, 0);
    }
#pragma unroll
  for (int m = 0; m < 2; ++m)
#pragma unroll
    for (int n = 0; n < 2; ++n)
#pragma unroll
      for (int reg = 0; reg < 4; ++reg)
        red[wv][m * 16 + kgrp * 4 + reg][n * 16 + r15] = g4[m][n][reg];
  __syncthreads();
  for (int idx = t; idx < 1024; idx += 256) {
    int r = idx >> 5, c = idx & 31;
    Gpart[(size_t)blockIdx.x * 1024 + idx] = red[0][r][c] + red[1][r][c] + red[2][r][c] + red[3][r][c];
  }
}

// ---------------- K7a: grid-parallel reduction of Rpart -> 128x30 partials ----------------
__global__ __launch_bounds__(64) void k_reduce1(const float* __restrict__ Rpart,
    const float* __restrict__ sT, const float* __restrict__ maxv,
    float* __restrict__ partials) {
  int t = threadIdx.x;
  int n = blockIdx.x * 64 + t;
  float rsum[28];
#pragma unroll
  for (int c = 0; c < 28; ++c) rsum[c] = 0.f;
#pragma unroll
  for (int bs = 0; bs < 16; ++bs)
#pragma unroll
    for (int c = 0; c < 28; ++c)
      rsum[c] += Rpart[((size_t)bs * 28 + c) * NTOT + n];
  float deg = rsum[0];
  float T1 = 0.f;
  float vloc[KCL];
#pragma unroll
  for (int k = 0; k < KCL; ++k) {
    float sv = sT[(size_t)k * NTOT + n];
    T1 += sv * rsum[1 + k];
    vloc[k] = deg * sv;
  }
  float mx = maxv[n];
  for (int o = 32; o; o >>= 1) {
    deg += __shfl_down(deg, o);
    T1 += __shfl_down(T1, o);
    mx += __shfl_down(mx, o);
  }
#pragma unroll
  for (int k = 0; k < KCL; ++k)
    for (int o = 32; o; o >>= 1) vloc[k] += __shfl_down(vloc[k], o);
  if (t == 0) {
    float* p = partials + blockIdx.x * 30;
    p[0] = deg; p[1] = T1; p[2] = mx;
#pragma unroll
    for (int k = 0; k < KCL; ++k) p[3 + k] = vloc[k];
  }
}

// ---------------- K7b: tiny final combine + ortho ----------------
__device__ float block_sum_1024(float v) {
  __shared__ float sc[16];
  for (int o = 32; o; o >>= 1) v += __shfl_down(v, o);
  __syncthreads();
  if ((threadIdx.x & 63) == 0) sc[threadIdx.x >> 6] = v;
  __syncthreads();
  if (threadIdx.x == 0) {
    float r = 0.f;
    for (int i = 0; i < 16; ++i) r += sc[i];
    sc[0] = r;
  }
  __syncthreads();
  return sc[0];
}

__global__ __launch_bounds__(1024) void k_final2(const float* __restrict__ partials,
    const float* __restrict__ Gpart, float* __restrict__ out) {
  __shared__ float comb[30];
  int t = threadIdx.x;
  if (t < 30) {
    float a = 0.f;
    for (int b = 0; b < 128; ++b) a += partials[b * 30 + t];
    comb[t] = a;
  }
  float val = 0.f;
  if (t < 729) {
    int k = t / 27, l = t - k * 27;
    int gidx = (k + 1) * 32 + (l + 1);
    for (int b = 0; b < 64; ++b) val += Gpart[(size_t)b * 1024 + gidx];
  }
  __syncthreads();
  float F2 = block_sum_1024(val * val);
  float F = sqrtf(F2);
  bool diag = (t < 729) && (t % 28 == 0);
  float gg = (t < 729) ? (val / F - (diag ? (1.f / sqrtf(27.f)) : 0.f)) : 0.f;
  float O2 = block_sum_1024(gg * gg);
  float ortho = sqrtf(O2);
  if (t == 0) {
    float sumDeg = comb[0], T1 = comb[1], maxsum = comb[2];
    float norm = 0.5f * sumDeg;
    float vv = 0.f;
    for (int k = 0; k < KCL; ++k) vv += comb[3 + k] * comb[3 + k];
    float c = 0.05f / (2.f * norm);
    float sm = -(T1 - c * vv) / (2.f * norm);
    float cl = -maxsum / (float)NTOT;
    out[0] = sm + cl + ortho;
    out[1] = sm;
  }
}

extern "C" void kernel_launch(void* const* d_in, const int* in_sizes, int n_in,
                              void* d_out, int out_size, void* d_ws, size_t ws_size,
                              hipStream_t stream) {
  const float* x        = (const float*)d_in[0];
  const float* clusters = (const float*)d_in[1];
  const float* alpha    = (const float*)d_in[2];
  float* out = (float*)d_out;
  float* ws  = (float*)d_ws;

  // workspace layout (float offsets)
  const size_t OFF_MBF  = 0;                                    // bf16 [8192][512]
  const size_t OFF_NCLB = (size_t)NTOT * CDIM / 2;              // bf16 [32][512]
  const size_t OFF_ST   = OFF_NCLB + (size_t)32 * CDIM / 2;     // f32 sT [27][8192]
  const size_t OFF_SXB  = OFF_ST + (size_t)NTOT * KCL;          // bf16 sxT [32][8192]
  const size_t OFF_MAXV = OFF_SXB + (size_t)32 * NTOT / 2;
  const size_t OFF_INVN = OFF_MAXV + NTOT;                      // f32 [8192]
  const size_t OFF_R    = OFF_INVN + NTOT;                      // Rpart: 16*28*8192 f32
  const size_t OFF_GP   = OFF_R + (size_t)16 * 28 * NTOT;       // Gpart: 64*1024 f32
  const size_t OFF_PART = OFF_GP + (size_t)64 * 1024;           // 128*30 partials

  unsigned short* mbf  = (unsigned short*)(ws + OFF_MBF);
  unsigned short* nclb = (unsigned short*)(ws + OFF_NCLB);
  unsigned short* sxbf = (unsigned short*)(ws + OFF_SXB);

  // no memsets needed: nclb rows 27-31 / sxbf rows 28-31 feed only output
  // columns >= 28, which are never read (PV write guarded c<28; k_final2
  // reads Gpart indices 1..27 only). Contents are replay-invariant.
  k_prep<<<155, 256, 0, stream>>>(x, clusters, ws + OFF_INVN, nclb);
  k_merged2<<<512, 256, 0, stream>>>(x, ws + OFF_INVN, mbf);
  k_inner2<<<256, 256, 0, stream>>>(mbf, nclb, alpha,
                                    ws + OFF_ST, ws + OFF_MAXV, out + 2, sxbf);
  k_fused<<<dim3(64, 16), 256, 0, stream>>>(mbf, sxbf, ws + OFF_R);
  k_sts2<<<64, 256, 0, stream>>>(sxbf, ws + OFF_GP);
  k_reduce1<<<128, 64, 0, stream>>>(ws + OFF_R, ws + OFF_ST, ws + OFF_MAXV,
                                    ws + OFF_PART);
  k_final2<<<1, 1024, 0, stream>>>(ws + OFF_PART, ws + OFF_GP, out);
}